// Round 2
// baseline (1175.457 us; speedup 1.0000x reference)
//
#include <hip/hip_runtime.h>

#define T_LEN 2048
#define BATCH 512
#define HID   25
#define NNOTES 51
#define EMBED 50
#define G4    100   // 4*HID

typedef float v2f __attribute__((ext_vector_type(2)));

#define REP25(M) M(0) M(1) M(2) M(3) M(4) M(5) M(6) M(7) M(8) M(9) \
  M(10) M(11) M(12) M(13) M(14) M(15) M(16) M(17) M(18) M(19) \
  M(20) M(21) M(22) M(23) M(24)

#define NL2E 1.442695041f   // log2(e)

#if __has_builtin(__builtin_amdgcn_exp2f)
#define EXP2(x) __builtin_amdgcn_exp2f(x)
#else
#define EXP2(x) __expf((x) * 0.6931471805599453f)
#endif

__device__ __forceinline__ float bcastf(float v, int lane) {
  return __int_as_float(__builtin_amdgcn_readlane(__float_as_int(v), lane));
}
__device__ __forceinline__ float rcpf_(float x) { return __builtin_amdgcn_rcpf(x); }
__device__ __forceinline__ v2f mk2(float a, float b) { v2f r; r.x = a; r.y = b; return r; }

// Pin a value into VGPRs: opaque def -> compiler cannot rematerialize/sink the
// originating load into the loop; the value must stay register-resident.
__device__ __forceinline__ void pin2(v2f& v) { asm volatile("" : "+v"(v)); }
__device__ __forceinline__ void pin1(float& v) { asm volatile("" : "+v"(v)); }

// zA carries sigmoid-rows (i or f); zB carries (g or o): lanes<25 need tanh on zB,
// lanes 25-49 need sigmoid. sB/aB/bB are per-lane constants selecting the variant.
__device__ __forceinline__ void gates(float zA, float zB, float& c, float& h,
                                      float sB, float aB, float bB, int paddr) {
  float uA = rcpf_(1.0f + EXP2(zA * (-NL2E)));          // sigmoid(zA)
  float eB = EXP2(zB * sB);
  float uB = rcpf_(1.0f + eB);
  float rB = fmaf(aB, uB, bB);                          // tanh(zB) or sigmoid(zB)
  float sf = __int_as_float(__builtin_amdgcn_ds_bpermute(paddr, __float_as_int(uA)));
  float so = __int_as_float(__builtin_amdgcn_ds_bpermute(paddr, __float_as_int(rB)));
  float cn = fmaf(sf, c, uA * rB);
  c = cn;
  float th = fmaf(2.0f, rcpf_(1.0f + EXP2(cn * (-2.0f * NL2E))), -1.0f);
  h = so * th;
}

// Kernel 1: proj[n][j] = bih0[j] + bhh0[j] + sum_e Wih0[j,e]*emb[n,e]
__global__ void build_proj(const float* __restrict__ emb,
                           const float* __restrict__ Wih0,
                           const float* __restrict__ bih0,
                           const float* __restrict__ bhh0,
                           float* __restrict__ proj) {
  const int n = blockIdx.x;
  const int j = threadIdx.x;
  if (j < G4) {
    float acc = bih0[j] + bhh0[j];
    #pragma unroll
    for (int e = 0; e < EMBED; ++e)
      acc = fmaf(Wih0[j * EMBED + e], emb[n * EMBED + e], acc);
    proj[n * G4 + j] = acc;
  }
}

// Kernel 2: one block (3 waves) per batch element, wave-specialized pipeline:
//   wave0: layer-0 recurrence + u(t) = b1 + Wih1 @ h0(t)   (100 weight VGPRs, pinned)
//   wave1: layer-1 recurrence z1 = u + Whh1 @ h1           ( 50 weight VGPRs, pinned)
//   wave2: FC head + global stores                         ( 25 weight VGPRs, pinned)
// One s_barrier per timestep; depth-2 rings. Barrier counts per wave: 1 + (T+2).
__global__ __launch_bounds__(192, 1) __attribute__((amdgpu_waves_per_eu(1)))
void lstm_seq(
    const int* __restrict__ x, const float* __restrict__ proj,
    const float* __restrict__ Whh0,
    const float* __restrict__ Wih1, const float* __restrict__ Whh1,
    const float* __restrict__ bih1, const float* __restrict__ bhh1,
    const float* __restrict__ fcW, const float* __restrict__ fcb,
    float* __restrict__ out) {
  __shared__ float projL[NNOTES * G4];   // 20400 B
  __shared__ int   xL[T_LEN];            //  8192 B
  __shared__ v2f   uRing[2][64];         //  1024 B : per-lane packed u = b1 + Wih1@h0
  __shared__ float h1Ring[2][HID];       //   200 B : h1 values (lanes 0..24)

  const int tid = threadIdx.x;
  const int l   = tid & 63;
  const int w   = __builtin_amdgcn_readfirstlane(tid >> 6);  // provably uniform
  const int b   = blockIdx.x;

  for (int i = tid; i < NNOTES * G4; i += 192) projL[i] = proj[i];
  const int* xrow = x + b * T_LEN;
  for (int i = tid; i < T_LEN; i += 192) xL[i] = xrow[i];
  __syncthreads();   // barrier #0 (all waves)

  const bool act = (l < 50);
  const bool lo  = (l < 25);
  const int jA = act ? l : 0;
  const int jB = act ? (l + 50) : 0;
  const int paddr = ((l + 25) & 63) << 2;

  const float sB = lo ? (-2.0f * NL2E) : (-NL2E);
  const float aB = lo ? 2.0f : 1.0f;
  const float bB = lo ? -1.0f : 0.0f;

  const size_t baseH = (size_t)BATCH * T_LEN * NNOTES;
  const size_t baseC = baseH + (size_t)2 * BATCH * HID;

  if (w == 0) {
    // -------- wave 0: layer 0 + input-projection of layer 1 --------
    v2f w0[HID], wi1[HID];
#define LDW0(i) \
    w0[i]  = act ? mk2(Whh0[jA*HID+(i)], Whh0[jB*HID+(i)]) : mk2(0.f,0.f); \
    wi1[i] = act ? mk2(Wih1[jA*HID+(i)], Wih1[jB*HID+(i)]) : mk2(0.f,0.f);
    REP25(LDW0)
#undef LDW0
    v2f b1 = act ? mk2(bih1[jA] + bhh1[jA], bih1[jB] + bhh1[jB]) : mk2(0.f, 0.f);
#define PIN0(i) pin2(w0[i]); pin2(wi1[i]);
    REP25(PIN0)
#undef PIN0
    pin2(b1);

    float h0 = 0.f, c0 = 0.f;
    float h0b[HID];
#define Z0(i) h0b[i] = 0.0f;
    REP25(Z0)
#undef Z0

    int n0 = xL[0];
    v2f xz = mk2(projL[n0 * G4 + jA], projL[n0 * G4 + jB]);

    for (int t = 0; t < T_LEN; ++t) {
      const v2f xzc = xz;
      { const int nn = xL[(t + 1) & (T_LEN - 1)];
        xz = mk2(projL[nn * G4 + jA], projL[nn * G4 + jB]); }

      // ---- layer 0 matvec: 4 chains ----
      v2f zp0 = xzc, zp1 = mk2(0.f,0.f), zp2 = mk2(0.f,0.f), zp3 = mk2(0.f,0.f);
#define L0S(i) { const v2f hh = { h0b[i], h0b[i] }; \
      if      (((i)&3)==0) zp0 = __builtin_elementwise_fma(w0[i], hh, zp0); \
      else if (((i)&3)==1) zp1 = __builtin_elementwise_fma(w0[i], hh, zp1); \
      else if (((i)&3)==2) zp2 = __builtin_elementwise_fma(w0[i], hh, zp2); \
      else                 zp3 = __builtin_elementwise_fma(w0[i], hh, zp3); }
      REP25(L0S)
#undef L0S
      const v2f z0 = (zp0 + zp1) + (zp2 + zp3);
      gates(z0.x, z0.y, c0, h0, sB, aB, bB, paddr);
#define BC0(i) h0b[i] = bcastf(h0, i);
      REP25(BC0)
#undef BC0

      // ---- u = b1 + Wih1 @ h0: 4 chains ----
      v2f u0 = b1, u1 = mk2(0.f,0.f), u2 = mk2(0.f,0.f), u3 = mk2(0.f,0.f);
#define US(i) { const v2f hh = { h0b[i], h0b[i] }; \
      if      (((i)&3)==0) u0 = __builtin_elementwise_fma(wi1[i], hh, u0); \
      else if (((i)&3)==1) u1 = __builtin_elementwise_fma(wi1[i], hh, u1); \
      else if (((i)&3)==2) u2 = __builtin_elementwise_fma(wi1[i], hh, u2); \
      else                 u3 = __builtin_elementwise_fma(wi1[i], hh, u3); }
      REP25(US)
#undef US
      uRing[t & 1][l] = (u0 + u1) + (u2 + u3);  // consumed by wave1 after next barrier
      __syncthreads();                    // barrier t+1
    }
    __syncthreads();                      // T+1
    __syncthreads();                      // T+2
    if (l < HID) {
      out[baseH + (size_t)b * HID + l] = h0;
      out[baseC + (size_t)b * HID + l] = c0;
    }
  } else if (w == 1) {
    // -------- wave 1: layer-1 recurrence --------
    v2f wh1[HID];
#define LDW1(i) wh1[i] = act ? mk2(Whh1[jA*HID+(i)], Whh1[jB*HID+(i)]) : mk2(0.f,0.f);
    REP25(LDW1)
#undef LDW1
#define PIN1(i) pin2(wh1[i]);
    REP25(PIN1)
#undef PIN1
    float h1 = 0.f, c1 = 0.f;
    float h1b[HID];
#define Z1(i) h1b[i] = 0.0f;
    REP25(Z1)
#undef Z1

    __syncthreads();                      // barrier 1 (skew: wait for u(0))
    for (int t = 0; t < T_LEN; ++t) {
      const v2f u = uRing[t & 1][l];      // ds_read_b64; matvec below is independent
      v2f y0 = mk2(0.f,0.f), y1 = mk2(0.f,0.f), y2 = mk2(0.f,0.f), y3 = mk2(0.f,0.f);
#define L1S(i) { const v2f hh = { h1b[i], h1b[i] }; \
      if      (((i)&3)==0) y0 = __builtin_elementwise_fma(wh1[i], hh, y0); \
      else if (((i)&3)==1) y1 = __builtin_elementwise_fma(wh1[i], hh, y1); \
      else if (((i)&3)==2) y2 = __builtin_elementwise_fma(wh1[i], hh, y2); \
      else                 y3 = __builtin_elementwise_fma(wh1[i], hh, y3); }
      REP25(L1S)
#undef L1S
      const v2f z1v = (u + y0) + (y1 + y2) + y3;
      gates(z1v.x, z1v.y, c1, h1, sB, aB, bB, paddr);
#define BC1(i) h1b[i] = bcastf(h1, i);
      REP25(BC1)
#undef BC1
      if (lo) h1Ring[t & 1][l] = h1;      // consumed by wave2 after next barrier
      __syncthreads();                    // barrier t+2
    }
    __syncthreads();                      // T+2
    if (l < HID) {
      out[baseH + (size_t)BATCH * HID + (size_t)b * HID + l] = h1;
      out[baseC + (size_t)BATCH * HID + (size_t)b * HID + l] = c1;
    }
  } else {
    // -------- wave 2: FC head + stores --------
    float fcw[HID];
#define LDF(i) fcw[i] = (l < NNOTES) ? fcW[l*HID+(i)] : 0.0f;
    REP25(LDF)
#undef LDF
#define PINF(i) pin1(fcw[i]);
    REP25(PINF)
#undef PINF
    const float fb = (l < NNOTES) ? fcb[l] : 0.0f;
    float* outrow = out + (size_t)b * T_LEN * NNOTES;

    __syncthreads();                      // barrier 1
    __syncthreads();                      // barrier 2 (skew: wait for h1(0))
    for (int t = 0; t < T_LEN; ++t) {
      const float hv = h1Ring[t & 1][lo ? l : 0];
      float h1s[HID];
#define BCF(i) h1s[i] = bcastf(hv, i);
      REP25(BCF)
#undef BCF
      float a0 = fb, a1 = 0.f, a2 = 0.f, a3 = 0.f;
#define FCS(i) { if      (((i)&3)==0) a0 = fmaf(fcw[i], h1s[i], a0); \
                 else if (((i)&3)==1) a1 = fmaf(fcw[i], h1s[i], a1); \
                 else if (((i)&3)==2) a2 = fmaf(fcw[i], h1s[i], a2); \
                 else                 a3 = fmaf(fcw[i], h1s[i], a3); }
      REP25(FCS)
#undef FCS
      if (l < NNOTES) outrow[t * NNOTES + l] = (a0 + a1) + (a2 + a3);
      // raw barrier: rendezvous without draining vmcnt, so the global stores'
      // completion latency never enters the pipeline's critical path. The LDS
      // read above is already consumed (data dep -> lgkmcnt waited) and this
      // wave writes no LDS. "memory" clobber stops compiler reordering.
      asm volatile("s_barrier" ::: "memory");  // barrier t+3
    }
  }
}

extern "C" void kernel_launch(void* const* d_in, const int* in_sizes, int n_in,
                              void* d_out, int out_size, void* d_ws, size_t ws_size,
                              hipStream_t stream) {
  const int*   x    = (const int*)d_in[0];
  const float* emb  = (const float*)d_in[1];
  const float* Wih0 = (const float*)d_in[2];
  const float* Whh0 = (const float*)d_in[3];
  const float* bih0 = (const float*)d_in[4];
  const float* bhh0 = (const float*)d_in[5];
  const float* Wih1 = (const float*)d_in[6];
  const float* Whh1 = (const float*)d_in[7];
  const float* bih1 = (const float*)d_in[8];
  const float* bhh1 = (const float*)d_in[9];
  const float* fcW  = (const float*)d_in[10];
  const float* fcb  = (const float*)d_in[11];
  float* out  = (float*)d_out;
  float* proj = (float*)d_ws;  // 51*100 floats = 20.4 KB

  build_proj<<<NNOTES, 128, 0, stream>>>(emb, Wih0, bih0, bhh0, proj);
  lstm_seq<<<BATCH, 192, 0, stream>>>(x, proj, Whh0, Wih1, Whh1, bih1, bhh1,
                                      fcW, fcb, out);
}

// Round 4
// 908.122 us; speedup vs baseline: 1.2944x; 1.2944x over previous
//
#include <hip/hip_runtime.h>

#define T_LEN 2048
#define BATCH 512
#define HID   25
#define NNOTES 51
#define EMBED 50
#define G4    100   // 4*HID

typedef float v2f __attribute__((ext_vector_type(2)));

#define REP25(M) M(0) M(1) M(2) M(3) M(4) M(5) M(6) M(7) M(8) M(9) \
  M(10) M(11) M(12) M(13) M(14) M(15) M(16) M(17) M(18) M(19) \
  M(20) M(21) M(22) M(23) M(24)

#define NL2E 1.442695041f   // log2(e)

#if __has_builtin(__builtin_amdgcn_exp2f)
#define EXP2(x) __builtin_amdgcn_exp2f(x)
#else
#define EXP2(x) __expf((x) * 0.6931471805599453f)
#endif

__device__ __forceinline__ float bcastf(float v, int lane) {
  return __int_as_float(__builtin_amdgcn_readlane(__float_as_int(v), lane));
}
__device__ __forceinline__ float rcpf_(float x) { return __builtin_amdgcn_rcpf(x); }
__device__ __forceinline__ v2f mk2(float a, float b) { v2f r; r.x = a; r.y = b; return r; }

// Pin: opaque def so the compiler cannot rematerialize the originating load
// inside the loop. Only safe when the branch's live set fits in ~100 VGPRs
// (learned r2: pinning 102 regs pushes them to AGPR/scratch and regresses).
__device__ __forceinline__ void pin2(v2f& v) { asm volatile("" : "+v"(v)); }
__device__ __forceinline__ void pin1(float& v) { asm volatile("" : "+v"(v)); }

// zA carries sigmoid-rows (i or f); zB carries (g or o): lanes<25 need tanh on zB,
// lanes 25-49 need sigmoid. sB/aB/bB are per-lane constants selecting the variant.
__device__ __forceinline__ void gates(float zA, float zB, float& c, float& h,
                                      float sB, float aB, float bB, int paddr) {
  float uA = rcpf_(1.0f + EXP2(zA * (-NL2E)));          // sigmoid(zA)
  float eB = EXP2(zB * sB);
  float uB = rcpf_(1.0f + eB);
  float rB = fmaf(aB, uB, bB);                          // tanh(zB) or sigmoid(zB)
  float sf = __int_as_float(__builtin_amdgcn_ds_bpermute(paddr, __float_as_int(uA)));
  float so = __int_as_float(__builtin_amdgcn_ds_bpermute(paddr, __float_as_int(rB)));
  float cn = fmaf(sf, c, uA * rB);
  c = cn;
  float th = fmaf(2.0f, rcpf_(1.0f + EXP2(cn * (-2.0f * NL2E))), -1.0f);
  h = so * th;
}

// Kernel 1: proj[n][j] = bih0[j] + bhh0[j] + sum_e Wih0[j,e]*emb[n,e]
__global__ void build_proj(const float* __restrict__ emb,
                           const float* __restrict__ Wih0,
                           const float* __restrict__ bih0,
                           const float* __restrict__ bhh0,
                           float* __restrict__ proj) {
  const int n = blockIdx.x;
  const int j = threadIdx.x;
  if (j < G4) {
    float acc = bih0[j] + bhh0[j];
    #pragma unroll
    for (int e = 0; e < EMBED; ++e)
      acc = fmaf(Wih0[j * EMBED + e], emb[n * EMBED + e], acc);
    proj[n * G4 + j] = acc;
  }
}

// Kernel 2: one block (4 waves) per batch element, wave-specialized pipeline.
// Each stage holds <=50 weight VGPRs so everything stays register-resident:
//   S0: layer-0 recurrence (Whh0)            -> h0Ring
//   S1: u = b1 + Wih1 @ h0 (Wih1)            -> uRing
//   S2: layer-1 recurrence (Whh1)            -> h1Ring
//   S3: FC head + global stores (fcW)
// One barrier per timestep per wave; depth-2 rings; skews 0/1/2/3.
// Barrier budget: every wave executes exactly 2052 s_barriers (audited — no
// deadlock; ring producer/consumer separated by >=1 barrier in both directions).
__global__ __launch_bounds__(256, 1)
void lstm_seq(
    const int* __restrict__ x, const float* __restrict__ proj,
    const float* __restrict__ Whh0,
    const float* __restrict__ Wih1, const float* __restrict__ Whh1,
    const float* __restrict__ bih1, const float* __restrict__ bhh1,
    const float* __restrict__ fcW, const float* __restrict__ fcb,
    float* __restrict__ out) {
  __shared__ float projL[NNOTES * G4];   // 20400 B
  __shared__ int   xL[T_LEN];            //  8192 B
  __shared__ float h0Ring[2][32];        //   256 B : h0 (lanes 0..24)
  __shared__ v2f   uRing[2][64];         //  1024 B : per-lane packed u
  __shared__ float h1Ring[2][32];        //   256 B : h1 (lanes 0..24)

  const int tid = threadIdx.x;
  const int l   = tid & 63;
  const int w   = __builtin_amdgcn_readfirstlane(tid >> 6);  // provably uniform
  const int b   = blockIdx.x;

  for (int i = tid; i < NNOTES * G4; i += 256) projL[i] = proj[i];
  const int* xrow = x + b * T_LEN;
  for (int i = tid; i < T_LEN; i += 256) xL[i] = xrow[i];
  __syncthreads();   // barrier #0 (all waves)

  const bool act = (l < 50);
  const bool lo  = (l < 25);
  const int jA = act ? l : 0;
  const int jB = act ? (l + 50) : 0;
  const int paddr = ((l + 25) & 63) << 2;

  const float sB = lo ? (-2.0f * NL2E) : (-NL2E);
  const float aB = lo ? 2.0f : 1.0f;
  const float bB = lo ? -1.0f : 0.0f;

  const size_t baseH = (size_t)BATCH * T_LEN * NNOTES;
  const size_t baseC = baseH + (size_t)2 * BATCH * HID;

  if (w == 0) {
    // -------- S0: layer-0 recurrence --------
    v2f w0[HID];
#define LDW0(i) w0[i] = act ? mk2(Whh0[jA*HID+(i)], Whh0[jB*HID+(i)]) : mk2(0.f,0.f);
    REP25(LDW0)
#undef LDW0
#define PIN0(i) pin2(w0[i]);
    REP25(PIN0)
#undef PIN0

    float h0 = 0.f, c0 = 0.f;
    float h0b[HID];
#define Z0(i) h0b[i] = 0.0f;
    REP25(Z0)
#undef Z0

    int n0 = xL[0];
    v2f xz = mk2(projL[n0 * G4 + jA], projL[n0 * G4 + jB]);

    for (int t = 0; t < T_LEN; ++t) {
      const v2f xzc = xz;
      { const int nn = xL[(t + 1) & (T_LEN - 1)];
        xz = mk2(projL[nn * G4 + jA], projL[nn * G4 + jB]); }

      v2f zp0 = xzc, zp1 = mk2(0.f,0.f), zp2 = mk2(0.f,0.f), zp3 = mk2(0.f,0.f);
#define L0S(i) { const v2f hh = { h0b[i], h0b[i] }; \
      if      (((i)&3)==0) zp0 = __builtin_elementwise_fma(w0[i], hh, zp0); \
      else if (((i)&3)==1) zp1 = __builtin_elementwise_fma(w0[i], hh, zp1); \
      else if (((i)&3)==2) zp2 = __builtin_elementwise_fma(w0[i], hh, zp2); \
      else                 zp3 = __builtin_elementwise_fma(w0[i], hh, zp3); }
      REP25(L0S)
#undef L0S
      const v2f z0 = (zp0 + zp1) + (zp2 + zp3);
      gates(z0.x, z0.y, c0, h0, sB, aB, bB, paddr);
#define BC0(i) h0b[i] = bcastf(h0, i);
      REP25(BC0)
#undef BC0
      if (lo) h0Ring[t & 1][l] = h0;
      __syncthreads();                    // barrier t+1
    }
    __syncthreads();                      // T+1
    __syncthreads();                      // T+2
    __syncthreads();                      // T+3
    if (l < HID) {
      out[baseH + (size_t)b * HID + l] = h0;
      out[baseC + (size_t)b * HID + l] = c0;
    }
  } else if (w == 1) {
    // -------- S1: u = b1 + Wih1 @ h0 --------
    v2f wi1[HID];
#define LDW1(i) wi1[i] = act ? mk2(Wih1[jA*HID+(i)], Wih1[jB*HID+(i)]) : mk2(0.f,0.f);
    REP25(LDW1)
#undef LDW1
    v2f b1 = act ? mk2(bih1[jA] + bhh1[jA], bih1[jB] + bhh1[jB]) : mk2(0.f, 0.f);
#define PIN1(i) pin2(wi1[i]);
    REP25(PIN1)
#undef PIN1
    pin2(b1);

    __syncthreads();                      // barrier 1 (skew: wait for h0(0))
    for (int t = 0; t < T_LEN; ++t) {
      const float hv = h0Ring[t & 1][lo ? l : 0];
      float h0s[HID];
#define BCU(i) h0s[i] = bcastf(hv, i);
      REP25(BCU)
#undef BCU
      v2f u0 = b1, u1 = mk2(0.f,0.f), u2 = mk2(0.f,0.f), u3 = mk2(0.f,0.f);
#define US(i) { const v2f hh = { h0s[i], h0s[i] }; \
      if      (((i)&3)==0) u0 = __builtin_elementwise_fma(wi1[i], hh, u0); \
      else if (((i)&3)==1) u1 = __builtin_elementwise_fma(wi1[i], hh, u1); \
      else if (((i)&3)==2) u2 = __builtin_elementwise_fma(wi1[i], hh, u2); \
      else                 u3 = __builtin_elementwise_fma(wi1[i], hh, u3); }
      REP25(US)
#undef US
      uRing[t & 1][l] = (u0 + u1) + (u2 + u3);
      __syncthreads();                    // barrier t+2
    }
    __syncthreads();                      // T+2
    __syncthreads();                      // T+3
  } else if (w == 2) {
    // -------- S2: layer-1 recurrence --------
    v2f wh1[HID];
#define LDW2(i) wh1[i] = act ? mk2(Whh1[jA*HID+(i)], Whh1[jB*HID+(i)]) : mk2(0.f,0.f);
    REP25(LDW2)
#undef LDW2
#define PIN2(i) pin2(wh1[i]);
    REP25(PIN2)
#undef PIN2
    float h1 = 0.f, c1 = 0.f;
    float h1b[HID];
#define Z1(i) h1b[i] = 0.0f;
    REP25(Z1)
#undef Z1

    __syncthreads();                      // barrier 1
    __syncthreads();                      // barrier 2 (skew: wait for u(0))
    for (int t = 0; t < T_LEN; ++t) {
      const v2f u = uRing[t & 1][l];      // ds_read_b64; matvec below independent
      v2f y0 = mk2(0.f,0.f), y1 = mk2(0.f,0.f), y2 = mk2(0.f,0.f), y3 = mk2(0.f,0.f);
#define L1S(i) { const v2f hh = { h1b[i], h1b[i] }; \
      if      (((i)&3)==0) y0 = __builtin_elementwise_fma(wh1[i], hh, y0); \
      else if (((i)&3)==1) y1 = __builtin_elementwise_fma(wh1[i], hh, y1); \
      else if (((i)&3)==2) y2 = __builtin_elementwise_fma(wh1[i], hh, y2); \
      else                 y3 = __builtin_elementwise_fma(wh1[i], hh, y3); }
      REP25(L1S)
#undef L1S
      const v2f z1v = (u + y0) + (y1 + y2) + y3;
      gates(z1v.x, z1v.y, c1, h1, sB, aB, bB, paddr);
#define BC1(i) h1b[i] = bcastf(h1, i);
      REP25(BC1)
#undef BC1
      if (lo) h1Ring[t & 1][l] = h1;
      __syncthreads();                    // barrier t+3
    }
    __syncthreads();                      // T+3
    if (l < HID) {
      out[baseH + (size_t)BATCH * HID + (size_t)b * HID + l] = h1;
      out[baseC + (size_t)BATCH * HID + (size_t)b * HID + l] = c1;
    }
  } else {
    // -------- S3: FC head + stores --------
    float fcw[HID];
#define LDF(i) fcw[i] = (l < NNOTES) ? fcW[l*HID+(i)] : 0.0f;
    REP25(LDF)
#undef LDF
#define PINF(i) pin1(fcw[i]);
    REP25(PINF)
#undef PINF
    const float fb = (l < NNOTES) ? fcb[l] : 0.0f;
    float* outrow = out + (size_t)b * T_LEN * NNOTES;

    __syncthreads();                      // barrier 1
    __syncthreads();                      // barrier 2
    __syncthreads();                      // barrier 3 (skew: wait for h1(0))
    for (int t = 0; t < T_LEN; ++t) {
      const float hv = h1Ring[t & 1][lo ? l : 0];
      float h1s[HID];
#define BCF(i) h1s[i] = bcastf(hv, i);
      REP25(BCF)
#undef BCF
      float a0 = fb, a1 = 0.f, a2 = 0.f, a3 = 0.f;
#define FCS(i) { if      (((i)&3)==0) a0 = fmaf(fcw[i], h1s[i], a0); \
                 else if (((i)&3)==1) a1 = fmaf(fcw[i], h1s[i], a1); \
                 else if (((i)&3)==2) a2 = fmaf(fcw[i], h1s[i], a2); \
                 else                 a3 = fmaf(fcw[i], h1s[i], a3); }
      REP25(FCS)
#undef FCS
      if (l < NNOTES) outrow[t * NNOTES + l] = (a0 + a1) + (a2 + a3);
      // raw barrier: rendezvous without draining vmcnt -> store completion
      // latency stays off the pipeline's critical path. The LDS read above is
      // already consumed (data dep forced lgkmcnt wait); this wave writes no LDS.
      asm volatile("s_barrier" ::: "memory");  // barrier t+4
    }
  }
}

extern "C" void kernel_launch(void* const* d_in, const int* in_sizes, int n_in,
                              void* d_out, int out_size, void* d_ws, size_t ws_size,
                              hipStream_t stream) {
  const int*   x    = (const int*)d_in[0];
  const float* emb  = (const float*)d_in[1];
  const float* Wih0 = (const float*)d_in[2];
  const float* Whh0 = (const float*)d_in[3];
  const float* bih0 = (const float*)d_in[4];
  const float* bhh0 = (const float*)d_in[5];
  const float* Wih1 = (const float*)d_in[6];
  const float* Whh1 = (const float*)d_in[7];
  const float* bih1 = (const float*)d_in[8];
  const float* bhh1 = (const float*)d_in[9];
  const float* fcW  = (const float*)d_in[10];
  const float* fcb  = (const float*)d_in[11];
  float* out  = (float*)d_out;
  float* proj = (float*)d_ws;  // 51*100 floats = 20.4 KB

  build_proj<<<NNOTES, 128, 0, stream>>>(emb, Wih0, bih0, bhh0, proj);
  lstm_seq<<<BATCH, 256, 0, stream>>>(x, proj, Whh0, Wih1, Whh1, bih1, bhh1,
                                      fcW, fcb, out);
}